// Round 1
// 640.574 us; speedup vs baseline: 1.4802x; 1.4802x over previous
//
#include <hip/hip_runtime.h>

// Problem constants (B=8192, N=8, H=256)
#define BB 8192
#define NSEG 8
#define HH 256
#define HO 128            // H/2
#define NODES 24          // 3N
#define EPER 90           // 6*(N-1) + 6*N
// Output layout (float32 elements, concatenated in return order)
#define NF_SIZE (BB * NODES * HH)          // 150994944
#define EI_OFF  NF_SIZE
#define EI_SIZE (2 * BB * EPER)            // 1474560
#define EA_OFF  (EI_OFF + EI_SIZE)         // 152469504
#define EA_SIZE (BB * EPER * 16)           // 11796480
#define BV_OFF  (EA_OFF + EA_SIZE)         // 164265984

// ---------------------------------------------------------------------------
// Pre-pass: W2T[kk][o] = float4(W[o][4kk..4kk+3]) for Wq then Wk.
// One-time 256 KB shuffle into d_ws so the main kernel's W loads are
// coalesced (consecutive lanes -> consecutive 16B).
// ---------------------------------------------------------------------------
__global__ __launch_bounds__(256) void transpose_w(
    const float4* __restrict__ Wq4, const float4* __restrict__ Wk4,
    float4* __restrict__ ws)
{
    int idx = blockIdx.x * 256 + threadIdx.x;   // 0..16383
    const float4* src = (idx < 8192) ? Wq4 : Wk4;
    int j  = idx & 8191;
    int o  = j >> 6;          // row 0..127
    int kk = j & 63;          // h-chunk 0..63
    float4 v = src[j];        // coalesced read
    ws[(idx & 8192) + kk * 128 + o] = v;        // scattered 16B write (one-time)
}

// ---------------------------------------------------------------------------
// Main kernel. TW=true: W read from transposed workspace (coalesced).
// TW=false: legacy per-lane row streaming (fallback if ws too small).
// ---------------------------------------------------------------------------
template <bool TW>
__global__ __launch_bounds__(256) void htdg_kernel(
    const float* __restrict__ zt, const float* __restrict__ za,
    const float* __restrict__ zf,
    const float* __restrict__ Wq, const float* __restrict__ bq,
    const float* __restrict__ Wk, const float* __restrict__ bk,
    const float* __restrict__ emb, const float4* __restrict__ wt,
    float* __restrict__ out)
{
    __shared__ float xs[NODES * HH];     // 24 KB: the sample's 24 node rows
    __shared__ float uv[32 * HO];        // 16 KB: u for a-slots 0..15, v for b-slots 16..31
    __shared__ float nrm_part[32 * 8];
    __shared__ float dot_part[24 * 8];
    __shared__ float rnorm_s[32];
    __shared__ float disc_s[24];
    __shared__ int   et_s[24];
    __shared__ float emb_s[40];

    const int b   = blockIdx.x;
    const int tid = threadIdx.x;

    // ---- Phase 0: stage nodes -> LDS, and write node_feats (pure copy) ----
    {
        float4*       xs4 = (float4*)xs;
        float4*       nf  = (float4*)out + (size_t)b * 1536;
        #pragma unroll
        for (int it = 0; it < 6; ++it) {
            int j = tid + it * 256;          // 0..1535 float4s of this sample
            int m = j >> 9;                  // modality (512 float4 each)
            int w = j & 511;
            const float4* sp = (m == 0 ? (const float4*)zt
                               : m == 1 ? (const float4*)za
                                        : (const float4*)zf) + (size_t)b * 512 + w;
            float4 v = *sp;
            xs4[j] = v;
            nf[j]  = v;
        }
        if (tid < 40) emb_s[tid] = emb[tid];
    }

    // ---- edge_index (180 floats) + batch_vec (24 floats), independent of LDS ----
    {
        int j = tid;
        if (j < 180) {
            int d = (j >= 90) ? 1 : 0;
            int e = j - d * 90;
            int s, dd;
            if (e < 42) {                       // temporal: m*14 + 2i + {0,1}
                int m = e / 14;
                int r = e - m * 14;
                int i = r >> 1;
                int u = m * 8 + i;
                if (r & 1) { s = u + 1; dd = u; } else { s = u; dd = u + 1; }
            } else {                            // cross: 42 + 2p + {0,1}
                int p  = (e - 42) >> 1;
                int pr = p >> 3;
                int i  = p & 7;
                int a  = (pr == 2 ? 8 : 0) + i;
                int bb = (pr == 0 ? 8 : 16) + i;
                if (e & 1) { s = bb; dd = a; } else { s = a; dd = bb; }
            }
            int val = ((d == 0) ? s : dd) + b * 24;
            out[(size_t)EI_OFF + (size_t)d * (BB * EPER) + (size_t)b * EPER + e] = (float)val;
        }
        if (tid < 24) out[(size_t)BV_OFF + (size_t)b * 24 + tid] = (float)b;
    }
    __syncthreads();

    // ---- Phase 1: matvec. waves 0,1 -> u=Wq*x for nodes 0..15 ; waves 2,3 -> v=Wk*x for nodes 8..23
    {
        const int wave = tid >> 6;
        const int lane = tid & 63;
        const float* bias;  int nodeBase, slotBase;
        if (wave < 2) { bias = bq; nodeBase = wave * 8;           slotBase = wave * 8; }
        else          { bias = bk; nodeBase = (wave - 2) * 8 + 8; slotBase = wave * 8; }

        // Coalesced path: W2T layout [kk][o], lanes read consecutive float4s.
        const float4* Wt = TW ? (wt + ((wave < 2) ? 0 : 8192)) : nullptr;
        // Legacy path: per-lane row streaming (1KB stride across lanes).
        const float*  Wb  = (wave < 2) ? Wq : Wk;
        const float4* Wr0 = (const float4*)Wb + (size_t)lane * 64;
        const float4* Wr1 = (const float4*)Wb + (size_t)(lane + 64) * 64;

        const float4* xb  = (const float4*)xs + nodeBase * 64;

        float acc0[8] = {0,0,0,0,0,0,0,0};
        float acc1[8] = {0,0,0,0,0,0,0,0};
        for (int kk = 0; kk < 64; ++kk) {
            float4 w0, w1;
            if (TW) {
                w0 = Wt[kk * 128 + lane];        // rows 0..63, coalesced 1KB/instr
                w1 = Wt[kk * 128 + 64 + lane];   // rows 64..127
            } else {
                w0 = Wr0[kk];
                w1 = Wr1[kk];
            }
            #pragma unroll
            for (int n = 0; n < 8; ++n) {
                float4 xv = xb[n * 64 + kk];   // same addr across lanes -> LDS broadcast
                acc0[n] += w0.x * xv.x + w0.y * xv.y + w0.z * xv.z + w0.w * xv.w;
                acc1[n] += w1.x * xv.x + w1.y * xv.y + w1.z * xv.z + w1.w * xv.w;
            }
        }
        float b0 = bias[lane], b1 = bias[lane + 64];
        #pragma unroll
        for (int n = 0; n < 8; ++n) {
            uv[(slotBase + n) * HO + lane]      = acc0[n] + b0;
            uv[(slotBase + n) * HO + 64 + lane] = acc1[n] + b1;
        }
    }
    __syncthreads();

    // ---- Phase 2: norms (32 tasks x 8 parts) and pair-dot partials (24 tasks x 8 parts) ----
    {
        int slot = tid >> 3, part = tid & 7;
        const float* u = &uv[slot * HO + part * 16];
        float s = 0.f;
        #pragma unroll
        for (int o = 0; o < 16; ++o) { float v = u[o]; s += v * v; }
        nrm_part[tid] = s;
    }
    if (tid < 192) {
        int p = tid >> 3, part = tid & 7;
        int pr = p >> 3, i = p & 7;
        int aslot = (pr == 2 ? 8 : 0) + i;
        int bslot = (pr == 0 ? 16 : 24) + i;
        const float* ua = &uv[aslot * HO + part * 16];
        const float* vb = &uv[bslot * HO + part * 16];
        float s = 0.f;
        #pragma unroll
        for (int o = 0; o < 16; ++o) s += ua[o] * vb[o];
        dot_part[tid] = s;
    }
    __syncthreads();
    if (tid < 32) {
        float s = 0.f;
        #pragma unroll
        for (int j = 0; j < 8; ++j) s += nrm_part[tid * 8 + j];
        rnorm_s[tid] = 1.0f / fmaxf(sqrtf(s), 1e-12f);
    }
    __syncthreads();
    if (tid < 24) {
        float s = 0.f;
        #pragma unroll
        for (int j = 0; j < 8; ++j) s += dot_part[tid * 8 + j];
        int pr = tid >> 3, i = tid & 7;
        int aslot = (pr == 2 ? 8 : 0) + i;
        int bslot = (pr == 0 ? 16 : 24) + i;
        float t   = s * rnorm_s[aslot] * rnorm_s[bslot];
        float dsc = 1.0f / (1.0f + expf(t));   // 1 - sigmoid(t)
        disc_s[tid] = dsc;
        et_s[tid]   = (dsc > 0.4f) ? 4 : 3;
    }
    __syncthreads();

    // ---- Phase 3: edge_attr (90 rows x 16 floats per sample) ----
    {
        float* ea = out + (size_t)EA_OFF + (size_t)b * (EPER * 16);
        #pragma unroll
        for (int it = 0; it < 6; ++it) {
            int j = tid + it * 256;
            if (j < 1440) {
                int row = j >> 4, c = j & 15;
                float val;
                if (row < 42) {
                    int m = row / 14;
                    if      (c < 8)   val = emb_s[m * 8 + c];
                    else if (c == 9)  val = 0.125f;
                    else if (c == 10) val = 1.0f;
                    else if (c == 11) val = (float)m * 0.25f;
                    else              val = 0.0f;
                } else {
                    int p  = (row - 42) >> 1;
                    int et = et_s[p];
                    if      (c < 8)   val = emb_s[et * 8 + c];
                    else if (c == 8)  val = disc_s[p];
                    else if (c == 11) val = (float)et * 0.25f;
                    else              val = 0.0f;
                }
                ea[j] = val;
            }
        }
    }
}

extern "C" void kernel_launch(void* const* d_in, const int* in_sizes, int n_in,
                              void* d_out, int out_size, void* d_ws, size_t ws_size,
                              hipStream_t stream) {
    const float* zt  = (const float*)d_in[0];
    const float* za  = (const float*)d_in[1];
    const float* zf  = (const float*)d_in[2];
    const float* Wq  = (const float*)d_in[3];
    const float* bq  = (const float*)d_in[4];
    const float* Wk  = (const float*)d_in[5];
    const float* bk  = (const float*)d_in[6];
    const float* emb = (const float*)d_in[7];

    if (d_ws && ws_size >= (size_t)2 * 8192 * sizeof(float4)) {
        float4* ws = (float4*)d_ws;
        transpose_w<<<64, 256, 0, stream>>>((const float4*)Wq, (const float4*)Wk, ws);
        htdg_kernel<true><<<BB, 256, 0, stream>>>(zt, za, zf, Wq, bq, Wk, bk, emb,
                                                  ws, (float*)d_out);
    } else {
        htdg_kernel<false><<<BB, 256, 0, stream>>>(zt, za, zf, Wq, bq, Wk, bk, emb,
                                                   nullptr, (float*)d_out);
    }
}